// Round 12
// baseline (345.741 us; speedup 1.0000x reference)
//
#include <hip/hip_runtime.h>
#include <hip/hip_bf16.h>
#include <hip/hip_fp16.h>

// TargetNet: per-sample MLP 2048->1024->512->256->128->1 over 64 samples x 256 spatial.
// R12 change vs R11 (304.9 us): L2+L3+L4+fc5 fused into ONE kernel (tail_fused, grid
// 256 = 1 block/CU, all co-resident). Per-sample spin barriers (device-scope atomics +
// threadfence) replace 2 kernel boundaries: no global layer drains, cross-sample overlap.
// Buffers de-aliased: xT@0, h1@64MiB, h2@98MiB, h3@115MiB, flags@124MiB (required now
// that samples run different layers concurrently). flags zeroed by transpose block 0.

typedef __attribute__((ext_vector_type(4)))  float    f32x4;
typedef __attribute__((ext_vector_type(16))) float    f32x16;
typedef __attribute__((ext_vector_type(8)))  short    short8;
typedef __attribute__((ext_vector_type(4)))  short    short4v;
typedef __attribute__((ext_vector_type(8)))  _Float16 half8;

__device__ __forceinline__ unsigned short f2h_bits(float f) {
  return __builtin_bit_cast(unsigned short, (_Float16)f);
}
__device__ __forceinline__ float h2f(short h) {
  return (float)__builtin_bit_cast(_Float16, (unsigned short)h);
}

// ---- transpose + convert: x [64][2048][256] f32 -> xT [64][256][2048] f16 ----
__global__ __launch_bounds__(256) void transpose_cvt(const float* __restrict__ X,
                                                     short* __restrict__ XT,
                                                     int* __restrict__ flags) {
  if (blockIdx.x == 0 && blockIdx.y == 0 && blockIdx.z == 0 && threadIdx.x < 64)
    flags[threadIdx.x] = 0;   // reset per-sample barrier counters each launch/replay
  __shared__ float tile[32][33];
  const int b  = blockIdx.z;
  const int c0 = blockIdx.x * 32, s0 = blockIdx.y * 32;
  const int tl = threadIdx.x & 31, tw = threadIdx.x >> 5;  // tw: 0..7
  const float* xp = X + ((size_t)b * 2048 + c0) * 256 + s0;
#pragma unroll
  for (int i = 0; i < 4; ++i) {
    const int c = tw * 4 + i;
    tile[c][tl] = xp[(size_t)c * 256 + tl];   // coalesced 128B rows
  }
  __syncthreads();
  short* op = XT + ((size_t)(b * 256 + s0)) * 2048 + c0;
#pragma unroll
  for (int i = 0; i < 4; ++i) {
    const int s = tw * 4 + i;
    op[(size_t)s * 2048 + tl] = (short)f2h_bits(tile[tl][s]);  // stride-33 LDS read: conflict-free
  }
}

// ---- per-sample GEMM layer phase (device function; body identical to R11 kernel) ----
// C[s, m] = sigmoid( sum_k W[m,k] * X[s,k] + bias[m] ), per sample b.
// A frag: lane l holds row (l&31), k = (l>>5)*8 + j  (f16 cvt from fp32 W, streamed once)
// B frag: lane l holds col (l&31), k = (l>>5)*8 + j  (16B ds_read from frag-ready LDS)
// C frag: col = lane&31, row = (reg&3) + 8*(reg>>2) + 4*(lane>>5)
template <int BK> struct WFrag { f32x4 v[BK / 8]; };

template <int M, int K, int WAVES, int NSPLIT, int BK, bool FUSE5>
__device__ __forceinline__ void gemm_phase(
    short* __restrict__ ldsb, short* __restrict__ epi,
    const float* __restrict__ W, const float* __restrict__ bias,
    const short* __restrict__ Xin, short* __restrict__ Out,
    const float* __restrict__ W5, const float* __restrict__ B5,
    float* __restrict__ out5, const int b, const int rem, const int tid) {
  constexpr int KH    = BK / 16;
  constexpr int NT    = K / BK;
  constexpr int NCG   = 8 / NSPLIT;
  constexpr int TILES = NCG * KH;
  constexpr int BM    = WAVES * 32;
  constexpr int MT    = M / BM;
  constexpr int TPW   = TILES / WAVES;
  constexpr int NS    = 256 / NSPLIT;
  constexpr int EPIW  = 40;
  constexpr int LHALF = TILES * 512;     // shorts per lds double-buffer half
  (void)MT;

  const int w = tid >> 6, l = tid & 63;
  const int lr = l & 31, lh = l >> 5;
  const int mt = rem / NSPLIT, ns = rem % NSPLIT;
  const int m0 = mt * BM + w * 32;

  const float* Wb = W + ((size_t)b * M + m0) * K;
  const short* Xb = Xin + (size_t)b * 256 * K + (size_t)ns * NS * K;

  f32x16 acc[NCG] = {};

  auto stage = [&](int buf, int t) {
    const int k0 = t * BK;
#pragma unroll
    for (int i = 0; i < TPW; ++i) {
      const int T  = w * TPW + i;
      const int s  = (T / KH) * 32 + lr;
      const int kk = (T % KH) * 16 + (lh << 3);
      const short* src = Xb + (size_t)s * K + k0 + kk;   // 16B per lane
      __builtin_amdgcn_global_load_lds(
          (const __attribute__((address_space(1))) void*)src,
          (__attribute__((address_space(3))) void*)&ldsb[buf * LHALF + T * 512],
          16, 0, 0);
    }
  };

  const float* wrow = Wb + (size_t)lr * K + (lh << 3);
  auto load_wfrag = [&](int t) {
    WFrag<BK> f;
#pragma unroll
    for (int h = 0; h < KH; ++h) {
      const float* wp = wrow + t * BK + h * 16;
      f.v[2 * h]     = *(const f32x4*)wp;
      f.v[2 * h + 1] = *(const f32x4*)(wp + 4);
    }
    return f;
  };

  WFrag<BK> wn;
  half8 wcH[KH];
  auto cvtW = [&]() {
#pragma unroll
    for (int h = 0; h < KH; ++h) {
#pragma unroll
      for (int j = 0; j < 4; ++j) {
        wcH[h][j]     = (_Float16)wn.v[2 * h][j];
        wcH[h][j + 4] = (_Float16)wn.v[2 * h + 1][j];
      }
    }
  };

  // prologue (vmcnt==0 on entry: __syncthreads/sample_barrier drained everything)
  stage(0, 0);
  asm volatile("" ::: "memory");
  wn = load_wfrag(0);
  asm volatile("" ::: "memory");
  stage(1, 1);
  asm volatile("" ::: "memory");
  cvtW();
  wn = load_wfrag(1);
  asm volatile("" ::: "memory");
  asm volatile("s_barrier" ::: "memory");
  __builtin_amdgcn_sched_barrier(0);

  // main loop: counted vmcnt keeps W(t+1) in flight across the barrier
  for (int t = 0; t < NT; ++t) {
    const int cur = t & 1;
#pragma unroll
    for (int h = 0; h < KH; ++h) {
#pragma unroll
      for (int cg = 0; cg < NCG; ++cg) {
        const short8 braw = *(const short8*)&ldsb[cur * LHALF + (cg * KH + h) * 512 + l * 8];
        acc[cg] = __builtin_amdgcn_mfma_f32_32x32x16_f16(wcH[h], __builtin_bit_cast(half8, braw),
                                                         acc[cg], 0, 0, 0);
      }
    }
    if (t + 1 < NT) {
      if constexpr (BK == 128) {
        asm volatile("s_waitcnt vmcnt(16)" ::: "memory");
      } else {
        asm volatile("s_waitcnt vmcnt(8)" ::: "memory");
      }
      __builtin_amdgcn_sched_barrier(0);
      asm volatile("s_barrier" ::: "memory");
      __builtin_amdgcn_sched_barrier(0);
      if (t + 2 < NT) {
        stage(cur, t + 2);
        asm volatile("" ::: "memory");
      }
      cvtW();
      if (t + 2 < NT) {
        wn = load_wfrag(t + 2);
        asm volatile("" ::: "memory");
      }
    }
  }

  // epilogue: bias + sigmoid, per-wave 32x32 LDS transpose
  float brow[16];
#pragma unroll
  for (int r = 0; r < 16; ++r) {
    const int row = (r & 3) + 8 * (r >> 2) + (lh << 2);
    brow[r] = bias[(size_t)b * M + m0 + row];
  }
  auto ep = [&](int wi, int s, int i) { return &epi[(((wi << 5) + s) * EPIW) + i]; };
  const int s_loc = l >> 1, hi = l & 1;
#pragma unroll
  for (int cg = 0; cg < NCG; ++cg) {
#pragma unroll
    for (int rg = 0; rg < 4; ++rg) {
      short4v pk;
#pragma unroll
      for (int j = 0; j < 4; ++j) {
        const int r = rg * 4 + j;
        float v = acc[cg][r] + brow[r];
        v = 1.0f / (1.0f + __expf(-v));
        pk[j] = (short)f2h_bits(v);
      }
      *(short4v*)ep(w, lr, rg * 8 + (lh << 2)) = pk;
    }
    if constexpr (!FUSE5) {
      const short8 r0 = *(const short8*)ep(w, s_loc, hi * 16);
      const short8 r1 = *(const short8*)ep(w, s_loc, hi * 16 + 8);
      short* op = Out + ((size_t)b * 256 + ns * NS + cg * 32 + s_loc) * M + m0 + hi * 16;
      *(short8*)op       = r0;
      *(short8*)(op + 8) = r1;
    } else {
      static_assert(!FUSE5 || (M == 128 && WAVES == 4), "FUSE5 needs full-M 4-wave block");
      __syncthreads();                    // epi complete across waves
      const int s_ = tid >> 3, r_ = tid & 7;   // 32 s x 8 cooperating lanes
      const short8 h0 = *(const short8*)ep(r_ >> 1, s_, (r_ & 1) * 16);
      const short8 h1 = *(const short8*)ep(r_ >> 1, s_, (r_ & 1) * 16 + 8);
      const float* wp = W5 + b * 128 + r_ * 16;
      const f32x4 w0 = *(const f32x4*)wp;
      const f32x4 w1 = *(const f32x4*)(wp + 4);
      const f32x4 w2 = *(const f32x4*)(wp + 8);
      const f32x4 w3 = *(const f32x4*)(wp + 12);
      float a = 0.f;
#pragma unroll
      for (int j = 0; j < 4; ++j) a += h2f(h0[j]) * w0[j];
#pragma unroll
      for (int j = 0; j < 4; ++j) a += h2f(h0[j + 4]) * w1[j];
#pragma unroll
      for (int j = 0; j < 4; ++j) a += h2f(h1[j]) * w2[j];
#pragma unroll
      for (int j = 0; j < 4; ++j) a += h2f(h1[j + 4]) * w3[j];
      a += __shfl_xor(a, 1);
      a += __shfl_xor(a, 2);
      a += __shfl_xor(a, 4);
      if (r_ == 0) out5[b * 256 + ns * NS + cg * 32 + s_] = 1.0f / (1.0f + __expf(-(a + B5[b])));
      __syncthreads();                    // before next cg overwrites epi
    }
  }
}

// ---- standalone layer kernel (L1) ----
template <int M, int K, int WAVES, int NSPLIT, int BK>
__global__ __launch_bounds__(WAVES * 64, 2) void gemm_layer(
    const float* __restrict__ W, const float* __restrict__ bias,
    const short* __restrict__ Xin, short* __restrict__ Out) {
  constexpr int NCG = 8 / NSPLIT, KH = BK / 16, TILES = NCG * KH;
  constexpr int PERB = (M / (WAVES * 32)) * NSPLIT;
  __shared__ __align__(16) short ldsb[2 * TILES * 512];
  __shared__ __align__(16) short epi[WAVES * 32 * 40];
  const int tid = threadIdx.x, bid = blockIdx.x;
  const int xcd = bid & 7, i_ = bid >> 3;
  const int b = xcd + 8 * (i_ / PERB);   // XCD-locality: siblings of b share an XCD
  const int rem = i_ % PERB;
  gemm_phase<M, K, WAVES, NSPLIT, BK, false>(ldsb, epi, W, bias, Xin, Out,
                                             nullptr, nullptr, nullptr, b, rem, tid);
}

// ---- per-sample spin barrier (device-scope; does NOT rely on XCD placement) ----
__device__ __forceinline__ void sample_barrier(int* flag, int target, int tid) {
  __syncthreads();                       // block's global stores drained (vmcnt 0)
  if (tid == 0) {
    __threadfence();                     // release: h-writes visible device-wide
    atomicAdd(flag, 1);
    while (atomicAdd(flag, 0) < target) __builtin_amdgcn_s_sleep(2);
    __threadfence();                     // acquire: invalidate stale cached lines
  }
  __syncthreads();
}

// ---- fused tail: L2 -> (per-sample bar) -> L3 -> (bar) -> L4+fc5 ----
__global__ __launch_bounds__(256, 2) void tail_fused(
    const float* __restrict__ W2, const float* __restrict__ b2,
    const float* __restrict__ W3, const float* __restrict__ b3,
    const float* __restrict__ W4, const float* __restrict__ b4,
    const float* __restrict__ W5, const float* __restrict__ B5,
    const short* __restrict__ h1, short* __restrict__ h2, short* __restrict__ h3,
    float* __restrict__ out, int* __restrict__ flags) {
  __shared__ __align__(16) short ldsb[2 * 32 * 512];   // max TILES (L2 phase) = 32
  __shared__ __align__(16) short epi[4 * 32 * 40];
  const int tid = threadIdx.x, bid = blockIdx.x;
  const int xcd = bid & 7, i_ = bid >> 3;
  const int b = xcd + 8 * (i_ >> 2);     // PERB = 4 in every phase
  const int rem = i_ & 3;
  // L2: 512x1024 (MT=4, NS=1) - W2 read once
  gemm_phase<512, 1024, 4, 1, 64, false>(ldsb, epi, W2, b2, h1, h2,
                                         nullptr, nullptr, nullptr, b, rem, tid);
  sample_barrier(&flags[b], 4, tid);
  // L3: 256x512 (MT=2, NS=2)
  gemm_phase<256, 512, 4, 2, 64, false>(ldsb, epi, W3, b3, h2, h3,
                                        nullptr, nullptr, nullptr, b, rem, tid);
  sample_barrier(&flags[b], 8, tid);
  // L4: 128x256 (MT=1, NS=4) + fused fc5 -> out
  gemm_phase<128, 256, 4, 4, 64, true>(ldsb, epi, W4, b4, h3, nullptr,
                                       W5, B5, out, b, rem, tid);
}

extern "C" void kernel_launch(void* const* d_in, const int* in_sizes, int n_in,
                              void* d_out, int out_size, void* d_ws, size_t ws_size,
                              hipStream_t stream) {
  const float* x  = (const float*)d_in[0];
  const float* w1 = (const float*)d_in[1];  const float* b1 = (const float*)d_in[2];
  const float* w2 = (const float*)d_in[3];  const float* b2 = (const float*)d_in[4];
  const float* w3 = (const float*)d_in[5];  const float* b3 = (const float*)d_in[6];
  const float* w4 = (const float*)d_in[7];  const float* b4 = (const float*)d_in[8];
  const float* w5 = (const float*)d_in[9];  const float* b5 = (const float*)d_in[10];

  char* ws = (char*)d_ws;
  short* xT    = (short*)ws;                           // 67,108,864 B
  short* h1    = (short*)(ws + 67108864ull);           // 33,554,432 B
  short* h2    = (short*)(ws + 102760448ull);          // 16,777,216 B
  short* h3    = (short*)(ws + 120586240ull);          //  8,388,608 B
  int*   flags = (int*)  (ws + 130023424ull);          //        256 B
  float* out   = (float*)d_out;

  // x -> xT (f16, [B,256,2048]); also zeroes flags (stream-ordered before tail_fused)
  transpose_cvt<<<dim3(64, 8, 64), 256, 0, stream>>>(x, xT, flags);
  // L1: 1024x2048, 8-wave BM=256 (MT=4), grid 256 = 1 block/CU
  gemm_layer<1024, 2048, 8, 1, 64><<<256, 512, 0, stream>>>(w1, b1, xT, h1);
  // L2+L3+L4+fc5 fused, grid 256 = 1 block/CU (co-resident; per-sample barriers)
  tail_fused<<<256, 256, 0, stream>>>(w2, b2, w3, b3, w4, b4, w5, b5,
                                      h1, h2, h3, out, flags);
}